// Round 1
// baseline (9115.446 us; speedup 1.0000x reference)
//
#include <hip/hip_runtime.h>
#include <cmath>

// ---------------- problem constants ----------------
#define B_   256
#define S_   512
#define H_   512
#define Z_   514            // SD + H
#define WUC  516            // WU_w cols: [x(2) | u(2) | h(512)]

// output float offsets
#define OUT_ZF   67371008   // B*S*Z
#define OUT_CZF  67502592   // + B*Z
#define OUT_COEF 67634176   // + B*Z

// ---------------- LDS layout (dynamic) ----------------
#define A_HI_OFF 0          // [32 rows][512 k] bf16 (swizzled)
#define A_LO_OFF 32768
#define CSCR_OFF 65536      // [8 kq*m][16 rows][84] f32 (cols 0..63 gates, 64..67 dots)
#define BIAS_OFF 108544     // [64]
#define WXU_OFF  108800     // [64][4]  (Wx0,Wx1,Wu0,Wu1 per gate-row)
#define XL_OFF   109824     // [32][2]  x state
#define PARS_OFF 110080     // A(4), Bm(2), alpha_b(2), Wh_b(2)
#define SMEM_BYTES 110144

typedef __attribute__((ext_vector_type(4))) float f32x4;
typedef __attribute__((ext_vector_type(8))) unsigned short us8;
typedef __attribute__((ext_vector_type(8))) __bf16 bf16x8;

__device__ __forceinline__ unsigned short f2bf(float f) {
  unsigned u = __float_as_uint(f);
  u += 0x7fffu + ((u >> 16) & 1u);          // round-to-nearest-even
  return (unsigned short)(u >> 16);
}
__device__ __forceinline__ float bf2f(unsigned short h) {
  return __uint_as_float(((unsigned)h) << 16);
}
// swizzled byte offset in A tiles: row in [0,32), k2 = 2*k byte offset (k in [0,512))
__device__ __forceinline__ int swz(int row, int k2) {
  int off = (row << 10) + k2;
  off ^= ((row & 7) << 4) ^ ((k2 & 0x380) >> 3);
  return off;
}
__device__ __forceinline__ f32x4 MF(us8 a, us8 b, f32x4 c) {
  return __builtin_amdgcn_mfma_f32_16x16x32_bf16(
      __builtin_bit_cast(bf16x8, a), __builtin_bit_cast(bf16x8, b), c, 0, 0, 0);
}
__device__ __forceinline__ void ast(float* p, float v) {
  __hip_atomic_store(p, v, __ATOMIC_RELAXED, __HIP_MEMORY_SCOPE_AGENT);
}
__device__ __forceinline__ float ald(const float* p) {
  return __hip_atomic_load((float*)p, __ATOMIC_RELAXED, __HIP_MEMORY_SCOPE_AGENT);
}
__device__ __forceinline__ float sigm(float x) { return 1.f / (1.f + expf(-x)); }

// grid: 256 blocks = bg(8) x gg(32); block: 512 threads = 8 waves
__global__ __launch_bounds__(512, 2) void lstm_persist(
    const float* __restrict__ rnn, const float* __restrict__ tau,
    const float* __restrict__ z0,  const float* __restrict__ c0,
    const float* __restrict__ wuw, const float* __restrict__ wub,
    const float* __restrict__ awp, const float* __restrict__ abp,
    const float* __restrict__ whw, const float* __restrict__ whb,
    const float* __restrict__ Amat, const float* __restrict__ Bmat,
    float* __restrict__ out, unsigned* __restrict__ bar)
{
  extern __shared__ __align__(16) char smem[];
  float* cscr = (float*)(smem + CSCR_OFF);
  float* bias = (float*)(smem + BIAS_OFF);
  float* wxu  = (float*)(smem + WXU_OFF);
  float* xl   = (float*)(smem + XL_OFF);
  float* pars = (float*)(smem + PARS_OFF);

  const int tid = threadIdx.x;
  const int blk = blockIdx.x;
  const int bg  = blk & 7;         // batch group -> rows [bg*32, bg*32+32)
  const int gg  = blk >> 3;        // gate group  -> units [gg*16, gg*16+16)
  const int rb0 = bg * 32;
  const int j0  = gg * 16;
  const int lane = tid & 63;
  const int wv   = tid >> 6;       // wave 0..7
  const int m    = wv & 1;         // M tile (16 rows)
  const int kq   = wv >> 1;        // K quarter (128)
  const int bb   = tid >> 4;       // 0..31 local batch row (pointwise mapping)
  const int jj   = tid & 15;       // unit-in-block / sub-index
  const int gb   = rb0 + bb;
  const int ln15 = lane & 15;
  const int lq   = lane >> 4;

  // ---------------- prologue ----------------
  // B fragments in registers: bf16 hi/lo split of WU_w h-part (+ alpha/Wh tile n=4)
  us8 bH[4][5], bL[4][5];
#pragma unroll
  for (int s = 0; s < 4; ++s) {
    const int kbase = kq * 128 + s * 32 + lq * 8;
#pragma unroll
    for (int n = 0; n < 4; ++n) {
      const float* wp = wuw + (size_t)(n * 512 + j0 + ln15) * WUC + 4 + kbase;
#pragma unroll
      for (int e = 0; e < 8; ++e) {
        float w = wp[e];
        unsigned short h = f2bf(w);
        bH[s][n][e] = h;
        bL[s][n][e] = f2bf(w - bf2f(h));
      }
    }
#pragma unroll
    for (int e = 0; e < 8; ++e) {   // n=4: [alpha_w ; Wh_w ; zeros] tile
      int k = kbase + e;
      float w = 0.f;
      if (ln15 < 2)      w = awp[ln15 * 512 + k];
      else if (ln15 < 4) w = whw[(ln15 - 2) * 512 + k];
      unsigned short h = f2bf(w);
      bH[s][4][e] = h;
      bL[s][4][e] = f2bf(w - bf2f(h));
    }
  }
  if (tid < 64) {
    int r = (tid >> 4) * 512 + j0 + (tid & 15);
    bias[tid] = wub[r];
    const float* wr = wuw + (size_t)r * WUC;
    wxu[tid * 4 + 0] = wr[0]; wxu[tid * 4 + 1] = wr[1];
    wxu[tid * 4 + 2] = wr[2]; wxu[tid * 4 + 3] = wr[3];
  }
  if (tid < 32) {
    xl[tid * 2 + 0] = z0[(size_t)(rb0 + tid) * Z_ + 0];
    xl[tid * 2 + 1] = z0[(size_t)(rb0 + tid) * Z_ + 1];
  }
  if (tid == 0) {
    pars[0] = Amat[0]; pars[1] = Amat[1]; pars[2] = Amat[2]; pars[3] = Amat[3];
    pars[4] = Bmat[0]; pars[5] = Bmat[1];
    pars[6] = abp[0];  pars[7] = abp[1];
    pars[8] = whb[0];  pars[9] = whb[1];
  }
  // A tiles from z0 h-part
#pragma unroll 4
  for (int i = 0; i < 32; ++i) {
    float hv = z0[(size_t)(rb0 + i) * Z_ + 2 + tid];
    unsigned short hh = f2bf(hv);
    unsigned short ll = f2bf(hv - bf2f(hh));
    int off = swz(i, tid * 2);
    *(unsigned short*)(smem + A_HI_OFF + off) = hh;
    *(unsigned short*)(smem + A_LO_OFF + off) = ll;
  }
  float c_state = c0[(size_t)gb * Z_ + 2 + j0 + jj];
  __syncthreads();

  // finalize x(tprev) from dot columns of cscr (threads with jj==0)
  auto xfin = [&](int tprev, bool tail_) {
    float d0 = 0, d1 = 0, d2 = 0, d3 = 0;
    const int mm = bb >> 4, rr = bb & 15;
#pragma unroll
    for (int q = 0; q < 4; ++q) {
      const float* cp = cscr + (size_t)(((q * 2 + mm) * 16 + rr)) * 84 + 64;
      d0 += cp[0]; d1 += cp[1]; d2 += cp[2]; d3 += cp[3];
    }
    const float al0 = sigm(d0 + pars[6]);
    const float al1 = sigm(d1 + pars[7]);
    const float wh0 = d2 + pars[8];
    const float wh1 = d3 + pars[9];
    const float tv  = tau[(size_t)gb * S_ + tprev];
    const float ud  = rnn[((size_t)gb * S_ + tprev) * 2 + 0];
    const float px0 = xl[bb * 2 + 0], px1 = xl[bb * 2 + 1];
    const float xm0 = px0 + tv * (pars[0] * px0 + pars[1] * px1 + pars[4] * ud);
    const float xm1 = px1 + tv * (pars[2] * px0 + pars[3] * px1 + pars[5] * ud);
    const float xn0 = al0 * xm0 + (1.f - al0) * wh0;
    const float xn1 = al1 * xm1 + (1.f - al1) * wh1;
    xl[bb * 2 + 0] = xn0; xl[bb * 2 + 1] = xn1;
    if (gg == 0) {
      size_t ob = ((size_t)gb * S_ + tprev) * Z_;
      ast(out + ob + 0, xn0); ast(out + ob + 1, xn1);
      size_t cb = OUT_COEF + ((size_t)gb * S_ + tprev) * 2;
      ast(out + cb + 0, al0); ast(out + cb + 1, al1);
      if (tail_) {
        ast(out + OUT_ZF  + (size_t)gb * Z_ + 0, xn0);
        ast(out + OUT_ZF  + (size_t)gb * Z_ + 1, xn1);
        ast(out + OUT_CZF + (size_t)gb * Z_ + 0, c0[(size_t)gb * Z_ + 0]);
        ast(out + OUT_CZF + (size_t)gb * Z_ + 1, c0[(size_t)gb * Z_ + 1]);
      }
    }
  };

  // ---------------- main loop ----------------
  for (int t = 0; t < S_; ++t) {
    // 1. GEMM: gates(t) from h(t-1); 5th tile = alpha/Wh dots of h(t-1)
    f32x4 a0 = {0,0,0,0}, a1 = {0,0,0,0}, a2 = {0,0,0,0}, a3 = {0,0,0,0}, a4 = {0,0,0,0};
    const int arow = m * 16 + ln15;
#pragma unroll
    for (int s = 0; s < 4; ++s) {
      const int kb  = kq * 128 + s * 32 + lq * 8;
      const int off = swz(arow, kb * 2);
      us8 ah = *(const us8*)(smem + A_HI_OFF + off);
      us8 al = *(const us8*)(smem + A_LO_OFF + off);
      a0 = MF(ah, bH[s][0], a0); a0 = MF(ah, bL[s][0], a0); a0 = MF(al, bH[s][0], a0);
      a1 = MF(ah, bH[s][1], a1); a1 = MF(ah, bL[s][1], a1); a1 = MF(al, bH[s][1], a1);
      a2 = MF(ah, bH[s][2], a2); a2 = MF(ah, bL[s][2], a2); a2 = MF(al, bH[s][2], a2);
      a3 = MF(ah, bH[s][3], a3); a3 = MF(ah, bL[s][3], a3); a3 = MF(al, bH[s][3], a3);
      a4 = MF(ah, bH[s][4], a4); a4 = MF(ah, bL[s][4], a4); a4 = MF(al, bH[s][4], a4);
    }
    {
      const int Rb = (kq * 2 + m) * 16 + lq * 4;
#pragma unroll
      for (int r = 0; r < 4; ++r) {
        float* cp = cscr + (size_t)(Rb + r) * 84;
        cp[0 * 16 + ln15] = a0[r];
        cp[1 * 16 + ln15] = a1[r];
        cp[2 * 16 + ln15] = a2[r];
        cp[3 * 16 + ln15] = a3[r];
        cp[4 * 16 + ln15] = a4[r];
      }
    }
    __syncthreads();
    // 2. finalize x(t-1) (needs dot cols of h(t-1))
    if (t > 0 && jj == 0) xfin(t - 1, false);
    __syncthreads();
    // 3. pointwise LSTM for (gb, j0+jj)
    float g0 = 0, g1 = 0, g2 = 0, g3 = 0;
    {
      const int mm = bb >> 4, rr = bb & 15;
#pragma unroll
      for (int q = 0; q < 4; ++q) {
        const float* cp = cscr + (size_t)(((q * 2 + mm) * 16 + rr)) * 84;
        g0 += cp[0 * 16 + jj]; g1 += cp[1 * 16 + jj];
        g2 += cp[2 * 16 + jj]; g3 += cp[3 * 16 + jj];
      }
    }
    {
      const float u0v = rnn[((size_t)gb * S_ + t) * 2 + 0];
      const float u1v = rnn[((size_t)gb * S_ + t) * 2 + 1];
      const float x0 = xl[bb * 2 + 0], x1 = xl[bb * 2 + 1];
      const float* w0 = wxu + (0 * 16 + jj) * 4;
      const float* w1 = wxu + (1 * 16 + jj) * 4;
      const float* w2 = wxu + (2 * 16 + jj) * 4;
      const float* w3 = wxu + (3 * 16 + jj) * 4;
      g0 += bias[0 * 16 + jj] + x0 * w0[0] + x1 * w0[1] + u0v * w0[2] + u1v * w0[3];
      g1 += bias[1 * 16 + jj] + x0 * w1[0] + x1 * w1[1] + u0v * w1[2] + u1v * w1[3];
      g2 += bias[2 * 16 + jj] + x0 * w2[0] + x1 * w2[1] + u0v * w2[2] + u1v * w2[3];
      g3 += bias[3 * 16 + jj] + x0 * w3[0] + x1 * w3[1] + u0v * w3[2] + u1v * w3[3];
    }
    const float ci = sigm(g0), cf = sigm(g1), co = sigm(g3);
    c_state = cf * c_state + ci * tanhf(g2);
    const float hval = co * tanhf(c_state);
    ast(out + ((size_t)gb * S_ + t) * Z_ + 2 + j0 + jj, hval);
    if (t == S_ - 1) {
      ast(out + OUT_ZF  + (size_t)gb * Z_ + 2 + j0 + jj, hval);
      ast(out + OUT_CZF + (size_t)gb * Z_ + 2 + j0 + jj, c_state);
    }
    // 4. per-batch-group barrier
    __syncthreads();
    if (tid == 0) {
      __hip_atomic_fetch_add(bar + bg, 1u, __ATOMIC_ACQ_REL, __HIP_MEMORY_SCOPE_AGENT);
      const unsigned tgt = 32u * (unsigned)(t + 1);
      while (__hip_atomic_load(bar + bg, __ATOMIC_ACQUIRE, __HIP_MEMORY_SCOPE_AGENT) < tgt)
        __builtin_amdgcn_s_sleep(2);
    }
    __syncthreads();
    // 5. rebuild A tiles from h(t) (in outputs buffer), coalesced: row i, k = tid
#pragma unroll 4
    for (int i = 0; i < 32; ++i) {
      float hv = ald(out + ((size_t)(rb0 + i) * S_ + t) * Z_ + 2 + tid);
      unsigned short hh = f2bf(hv);
      unsigned short ll = f2bf(hv - bf2f(hh));
      int off = swz(i, tid * 2);
      *(unsigned short*)(smem + A_HI_OFF + off) = hh;
      *(unsigned short*)(smem + A_LO_OFF + off) = ll;
    }
    __syncthreads();
  }

  // ---------------- tail: alpha/x for t = 511 ----------------
  {
    f32x4 a4 = {0,0,0,0};
    const int arow = m * 16 + ln15;
#pragma unroll
    for (int s = 0; s < 4; ++s) {
      const int kb  = kq * 128 + s * 32 + lq * 8;
      const int off = swz(arow, kb * 2);
      us8 ah = *(const us8*)(smem + A_HI_OFF + off);
      us8 al = *(const us8*)(smem + A_LO_OFF + off);
      a4 = MF(ah, bH[s][4], a4); a4 = MF(ah, bL[s][4], a4); a4 = MF(al, bH[s][4], a4);
    }
    const int Rb = (kq * 2 + m) * 16 + lq * 4;
#pragma unroll
    for (int r = 0; r < 4; ++r)
      cscr[(size_t)(Rb + r) * 84 + 64 + ln15] = a4[r];
  }
  __syncthreads();
  if (jj == 0) xfin(S_ - 1, true);
}

extern "C" void kernel_launch(void* const* d_in, const int* in_sizes, int n_in,
                              void* d_out, int out_size, void* d_ws, size_t ws_size,
                              hipStream_t stream) {
  const float* rnn  = (const float*)d_in[0];
  const float* tauP = (const float*)d_in[1];
  const float* z0   = (const float*)d_in[2];
  const float* c0   = (const float*)d_in[3];
  const float* wuw  = (const float*)d_in[4];
  const float* wub  = (const float*)d_in[5];
  const float* awp  = (const float*)d_in[6];
  const float* abp  = (const float*)d_in[7];
  const float* whw  = (const float*)d_in[8];
  const float* whb  = (const float*)d_in[9];
  const float* Amat = (const float*)d_in[10];
  const float* Bmat = (const float*)d_in[11];
  float* out = (float*)d_out;
  unsigned* bar = (unsigned*)d_ws;

  // reset barrier counters every call (determinism across graph replays)
  hipMemsetAsync(d_ws, 0, 64, stream);
  static bool attr_set = false;
  hipFuncSetAttribute((const void*)lstm_persist,
                      hipFuncAttributeMaxDynamicSharedMemorySize, SMEM_BYTES);
  (void)attr_set; (void)in_sizes; (void)n_in; (void)out_size; (void)ws_size;

  hipLaunchKernelGGL(lstm_persist, dim3(256), dim3(512), SMEM_BYTES, stream,
                     rnn, tauP, z0, c0, wuw, wub, awp, abp, whw, whb, Amat, Bmat,
                     out, bar);
}

// Round 2
// 2434.585 us; speedup vs baseline: 3.7441x; 3.7441x over previous
//
#include <hip/hip_runtime.h>
#include <cmath>

// ---------------- problem constants ----------------
#define B_   256
#define S_   512
#define Z_   514            // SD + H
#define WUC  516            // WU_w cols: [x(2) | u(2) | h(512)]

// output float offsets
#define OUT_ZF   67371008   // B*S*Z
#define OUT_CZF  67502592   // + B*Z
#define OUT_COEF 67634176   // + B*Z

// ---------------- workspace layout ----------------
// [0, 32KB)            : flags, 256 blocks x 128B (one u32 used per 128B line)
// [32KB, 32KB+1MB)     : h images, [parity(2)][bg(8)] x 64KB
//                        per image: hi bf16 [32 rows][512 cols] (32KB) then lo (32KB)
#define FLAGS_BYTES 32768
#define IMG_BYTES   65536
// total ws use = 32768 + 2*8*65536 = 1,081,344 bytes

typedef __attribute__((ext_vector_type(4))) float f32x4;
typedef __attribute__((ext_vector_type(4))) unsigned u32x4;
typedef __attribute__((ext_vector_type(8))) unsigned short us8;
typedef __attribute__((ext_vector_type(8))) __bf16 bf16x8;

__device__ __forceinline__ unsigned f2bf(float f) {
  unsigned u = __float_as_uint(f);
  u += 0x7fffu + ((u >> 16) & 1u);          // round-to-nearest-even
  return (u >> 16) & 0xffffu;
}
__device__ __forceinline__ float bf2f(unsigned h) {
  return __uint_as_float(h << 16);
}
__device__ __forceinline__ f32x4 MF(us8 a, us8 b, f32x4 c) {
  return __builtin_amdgcn_mfma_f32_16x16x32_bf16(
      __builtin_bit_cast(bf16x8, a), __builtin_bit_cast(bf16x8, b), c, 0, 0, 0);
}
__device__ __forceinline__ void ast32(unsigned* p, unsigned v) {
  __hip_atomic_store(p, v, __ATOMIC_RELAXED, __HIP_MEMORY_SCOPE_AGENT);
}
__device__ __forceinline__ unsigned ald32(const unsigned* p) {
  return __hip_atomic_load((unsigned*)p, __ATOMIC_RELAXED, __HIP_MEMORY_SCOPE_AGENT);
}
// 16B coherent load: bypass L1/L2 (agent scope), served at the L3 coherence point
__device__ __forceinline__ u32x4 ld16_sc(const void* p) {
  u32x4 r;
  asm volatile("global_load_dwordx4 %0, %1, off sc0 sc1" : "=v"(r) : "v"(p));
  return r;
}
__device__ __forceinline__ float sigm(float x) { return 1.f / (1.f + expf(-x)); }

// grid: 256 blocks = bg(8) x gg(32); block: 512 threads = 8 waves
__global__ __launch_bounds__(512, 2) void lstm_persist(
    const float* __restrict__ rnn, const float* __restrict__ tau,
    const float* __restrict__ z0,  const float* __restrict__ c0,
    const float* __restrict__ wuw, const float* __restrict__ wub,
    const float* __restrict__ awp, const float* __restrict__ abp,
    const float* __restrict__ whw, const float* __restrict__ whb,
    const float* __restrict__ Amat, const float* __restrict__ Bmat,
    float* __restrict__ out, unsigned* __restrict__ flags, char* __restrict__ img)
{
  __shared__ float cscr[8 * 16 * 84];   // 43 KB: gate partials + alpha/Wh dot cols

  const int tid = threadIdx.x;
  const int blk = blockIdx.x;
  const int bg  = blk & 7;         // batch group -> rows [bg*32, bg*32+32)
  const int gg  = blk >> 3;        // gate group  -> units [gg*16, gg*16+16)
  const int rb0 = bg * 32;
  const int j0  = gg * 16;
  const int lane = tid & 63;
  const int wv   = tid >> 6;       // wave 0..7
  const int m    = wv & 1;         // M tile (16 rows)
  const int kq   = wv >> 1;        // K quarter (128)
  const int bb   = tid >> 4;       // 0..31 local batch row (pointwise mapping)
  const int jj   = tid & 15;       // unit-in-block
  const int gb   = rb0 + bb;
  const int ln15 = lane & 15;
  const int lq   = lane >> 4;

  // ---------------- prologue: weights -> registers ----------------
  us8 bH[4][5], bL[4][5];
#pragma unroll
  for (int s = 0; s < 4; ++s) {
    const int kbase = kq * 128 + s * 32 + lq * 8;
#pragma unroll
    for (int n = 0; n < 4; ++n) {
      const float* wp = wuw + (size_t)(n * 512 + j0 + ln15) * WUC + 4 + kbase;
#pragma unroll
      for (int e = 0; e < 8; ++e) {
        float w = wp[e];
        unsigned h = f2bf(w);
        bH[s][n][e] = (unsigned short)h;
        bL[s][n][e] = (unsigned short)f2bf(w - bf2f(h));
      }
    }
#pragma unroll
    for (int e = 0; e < 8; ++e) {   // n=4: [alpha_w ; Wh_w ; zeros] tile
      int k = kbase + e;
      float w = 0.f;
      if (ln15 < 2)      w = awp[ln15 * 512 + k];
      else if (ln15 < 4) w = whw[(ln15 - 2) * 512 + k];
      unsigned h = f2bf(w);
      bH[s][4][e] = (unsigned short)h;
      bL[s][4][e] = (unsigned short)f2bf(w - bf2f(h));
    }
  }
  // small params, per-thread registers
  const float pA00 = Amat[0], pA01 = Amat[1], pA10 = Amat[2], pA11 = Amat[3];
  const float pB0 = Bmat[0], pB1 = Bmat[1];
  const float pab0 = abp[0], pab1 = abp[1], pwb0 = whb[0], pwb1 = whb[1];
  float gbias[4], gw[4][4];
#pragma unroll
  for (int n = 0; n < 4; ++n) {
    const int r = n * 512 + j0 + jj;
    gbias[n] = wub[r];
    const float* wr = wuw + (size_t)r * WUC;
    gw[n][0] = wr[0]; gw[n][1] = wr[1]; gw[n][2] = wr[2]; gw[n][3] = wr[3];
  }
  // states (x replicated across the 16 threads of each bb-group; identical math)
  float px0 = z0[(size_t)gb * Z_ + 0], px1 = z0[(size_t)gb * Z_ + 1];
  float c_state = c0[(size_t)gb * Z_ + 2 + j0 + jj];
  float u0_prev = 0.f, tau_prev = 0.f, hval = 0.f;

  // publish z0 h-slice into parity-1 image
  {
    float hv = z0[(size_t)gb * Z_ + 2 + j0 + jj];
    unsigned hh = f2bf(hv);
    unsigned ll = f2bf(hv - bf2f(hh));
    unsigned ph = (unsigned)__shfl_xor((int)hh, 1);
    unsigned pl = (unsigned)__shfl_xor((int)ll, 1);
    if ((jj & 1) == 0) {
      char* baseW = img + (size_t)(1 * 8 + bg) * IMG_BYTES;
      const int boff = bb * 1024 + (j0 + jj) * 2;
      ast32((unsigned*)(baseW + boff),          hh | (ph << 16));
      ast32((unsigned*)(baseW + 32768 + boff),  ll | (pl << 16));
    }
  }
  asm volatile("s_waitcnt vmcnt(0)" ::: "memory");
  __syncthreads();
  if (tid == 0) ast32(flags + blk * 32, 1u);

  const size_t fragoff = (size_t)(m * 16 + ln15) * 1024 + kq * 256 + lq * 16;
  const int mm = bb >> 4, rr = bb & 15;

  // ---------------- main loop ----------------
  for (int t = 0; t < S_; ++t) {
    const float u0v = rnn[((size_t)gb * S_ + t) * 2 + 0];
    const float u1v = rnn[((size_t)gb * S_ + t) * 2 + 1];
    const float tv  = tau[(size_t)gb * S_ + t];

    // wait: all 32 blocks of this bg have published h(t-1)  (flags on distinct lines)
    if (tid < 32) {
      const unsigned* f = flags + (tid * 8 + bg) * 32;
      const unsigned tgt = (unsigned)(t + 1);
      while (ald32(f) < tgt) __builtin_amdgcn_s_sleep(1);
    }
    __syncthreads();

    // GEMM over h(t-1): A-frags straight from the global image (coherent 16B loads)
    const char* baseR = img + (size_t)((((t & 1) ^ 1)) * 8 + bg) * IMG_BYTES + fragoff;
    u32x4 AH[4], AL[4];
#pragma unroll
    for (int s = 0; s < 4; ++s) {
      AH[s] = ld16_sc(baseR + s * 64);
      AL[s] = ld16_sc(baseR + 32768 + s * 64);
    }
    asm volatile("s_waitcnt vmcnt(0)" ::: "memory");
    __builtin_amdgcn_sched_barrier(0);

    f32x4 a0 = {0,0,0,0}, a1 = {0,0,0,0}, a2 = {0,0,0,0}, a3 = {0,0,0,0}, a4 = {0,0,0,0};
#pragma unroll
    for (int s = 0; s < 4; ++s) {
      us8 ah = __builtin_bit_cast(us8, AH[s]);
      us8 al = __builtin_bit_cast(us8, AL[s]);
      a0 = MF(ah, bH[s][0], a0); a0 = MF(ah, bL[s][0], a0); a0 = MF(al, bH[s][0], a0);
      a1 = MF(ah, bH[s][1], a1); a1 = MF(ah, bL[s][1], a1); a1 = MF(al, bH[s][1], a1);
      a2 = MF(ah, bH[s][2], a2); a2 = MF(ah, bL[s][2], a2); a2 = MF(al, bH[s][2], a2);
      a3 = MF(ah, bH[s][3], a3); a3 = MF(ah, bL[s][3], a3); a3 = MF(al, bH[s][3], a3);
      a4 = MF(ah, bH[s][4], a4); a4 = MF(ah, bL[s][4], a4); a4 = MF(al, bH[s][4], a4);
    }
    {
      const int Rb = (kq * 2 + m) * 16 + lq * 4;
#pragma unroll
      for (int r = 0; r < 4; ++r) {
        float* cp = cscr + (size_t)(Rb + r) * 84;
        cp[0 * 16 + ln15] = a0[r];
        cp[1 * 16 + ln15] = a1[r];
        cp[2 * 16 + ln15] = a2[r];
        cp[3 * 16 + ln15] = a3[r];
        cp[4 * 16 + ln15] = a4[r];
      }
    }
    __syncthreads();

    // gate sums + alpha/Wh dots (dots broadcast-read by all threads of a bb-group)
    float g0 = 0, g1 = 0, g2 = 0, g3 = 0, d0 = 0, d1 = 0, d2 = 0, d3 = 0;
#pragma unroll
    for (int q = 0; q < 4; ++q) {
      const float* cp = cscr + (size_t)((q * 2 + mm) * 16 + rr) * 84;
      g0 += cp[0 * 16 + jj]; g1 += cp[1 * 16 + jj];
      g2 += cp[2 * 16 + jj]; g3 += cp[3 * 16 + jj];
      d0 += cp[64]; d1 += cp[65]; d2 += cp[66]; d3 += cp[67];
    }
    // finalize x(t-1) (replicated per-thread; uniform within each bb-group)
    if (t > 0) {
      const float al0 = sigm(d0 + pab0), al1 = sigm(d1 + pab1);
      const float wh0 = d2 + pwb0, wh1 = d3 + pwb1;
      const float xm0 = px0 + tau_prev * (pA00 * px0 + pA01 * px1 + pB0 * u0_prev);
      const float xm1 = px1 + tau_prev * (pA10 * px0 + pA11 * px1 + pB1 * u0_prev);
      px0 = al0 * xm0 + (1.f - al0) * wh0;
      px1 = al1 * xm1 + (1.f - al1) * wh1;
      if (gg == 0 && jj == 0) {
        const size_t ob = ((size_t)gb * S_ + (t - 1)) * Z_;
        __builtin_nontemporal_store(px0, out + ob + 0);
        __builtin_nontemporal_store(px1, out + ob + 1);
        const size_t cb = OUT_COEF + ((size_t)gb * S_ + (t - 1)) * 2;
        __builtin_nontemporal_store(al0, out + cb + 0);
        __builtin_nontemporal_store(al1, out + cb + 1);
      }
    }
    // pointwise LSTM
    g0 += gbias[0] + px0 * gw[0][0] + px1 * gw[0][1] + u0v * gw[0][2] + u1v * gw[0][3];
    g1 += gbias[1] + px0 * gw[1][0] + px1 * gw[1][1] + u0v * gw[1][2] + u1v * gw[1][3];
    g2 += gbias[2] + px0 * gw[2][0] + px1 * gw[2][1] + u0v * gw[2][2] + u1v * gw[2][3];
    g3 += gbias[3] + px0 * gw[3][0] + px1 * gw[3][1] + u0v * gw[3][2] + u1v * gw[3][3];
    const float ci = sigm(g0), cf = sigm(g1), co = sigm(g3);
    c_state = cf * c_state + ci * tanhf(g2);
    hval = co * tanhf(c_state);
    u0_prev = u0v; tau_prev = tv;

    // publish h(t) -> parity t&1 (hi/lo pair-packed via shfl)
    {
      unsigned hh = f2bf(hval);
      unsigned ll = f2bf(hval - bf2f(hh));
      unsigned ph = (unsigned)__shfl_xor((int)hh, 1);
      unsigned pl = (unsigned)__shfl_xor((int)ll, 1);
      if ((jj & 1) == 0) {
        char* baseW = img + (size_t)((t & 1) * 8 + bg) * IMG_BYTES;
        const int boff = bb * 1024 + (j0 + jj) * 2;
        ast32((unsigned*)(baseW + boff),         hh | (ph << 16));
        ast32((unsigned*)(baseW + 32768 + boff), ll | (pl << 16));
      }
    }
    asm volatile("s_waitcnt vmcnt(0)" ::: "memory");   // drain before flag
    __syncthreads();
    if (tid == 0) ast32(flags + blk * 32, (unsigned)(t + 2));

    // harness output h (off the critical path, after the flag)
    __builtin_nontemporal_store(hval, out + ((size_t)gb * S_ + t) * Z_ + 2 + j0 + jj);
  }

  // ---------------- tail ----------------
  __builtin_nontemporal_store(hval,    out + OUT_ZF  + (size_t)gb * Z_ + 2 + j0 + jj);
  __builtin_nontemporal_store(c_state, out + OUT_CZF + (size_t)gb * Z_ + 2 + j0 + jj);

  if (tid < 32) {
    const unsigned* f = flags + (tid * 8 + bg) * 32;
    while (ald32(f) < (unsigned)(S_ + 1)) __builtin_amdgcn_s_sleep(1);
  }
  __syncthreads();
  {
    const char* baseR = img + (size_t)(1 * 8 + bg) * IMG_BYTES + fragoff;  // h(511) at parity 1
    f32x4 a4 = {0,0,0,0};
#pragma unroll
    for (int s = 0; s < 4; ++s) {
      u32x4 AHs = ld16_sc(baseR + s * 64);
      u32x4 ALs = ld16_sc(baseR + 32768 + s * 64);
      asm volatile("s_waitcnt vmcnt(0)" ::: "memory");
      __builtin_amdgcn_sched_barrier(0);
      us8 ah = __builtin_bit_cast(us8, AHs);
      us8 al = __builtin_bit_cast(us8, ALs);
      a4 = MF(ah, bH[s][4], a4); a4 = MF(ah, bL[s][4], a4); a4 = MF(al, bH[s][4], a4);
    }
    const int Rb = (kq * 2 + m) * 16 + lq * 4;
#pragma unroll
    for (int r = 0; r < 4; ++r)
      cscr[(size_t)(Rb + r) * 84 + 64 + ln15] = a4[r];
  }
  __syncthreads();
  {
    float d0 = 0, d1 = 0, d2 = 0, d3 = 0;
#pragma unroll
    for (int q = 0; q < 4; ++q) {
      const float* cp = cscr + (size_t)((q * 2 + mm) * 16 + rr) * 84;
      d0 += cp[64]; d1 += cp[65]; d2 += cp[66]; d3 += cp[67];
    }
    const float al0 = sigm(d0 + pab0), al1 = sigm(d1 + pab1);
    const float wh0 = d2 + pwb0, wh1 = d3 + pwb1;
    const float xm0 = px0 + tau_prev * (pA00 * px0 + pA01 * px1 + pB0 * u0_prev);
    const float xm1 = px1 + tau_prev * (pA10 * px0 + pA11 * px1 + pB1 * u0_prev);
    const float xn0 = al0 * xm0 + (1.f - al0) * wh0;
    const float xn1 = al1 * xm1 + (1.f - al1) * wh1;
    if (gg == 0 && jj == 0) {
      const size_t ob = ((size_t)gb * S_ + (S_ - 1)) * Z_;
      __builtin_nontemporal_store(xn0, out + ob + 0);
      __builtin_nontemporal_store(xn1, out + ob + 1);
      const size_t cb = OUT_COEF + ((size_t)gb * S_ + (S_ - 1)) * 2;
      __builtin_nontemporal_store(al0, out + cb + 0);
      __builtin_nontemporal_store(al1, out + cb + 1);
      __builtin_nontemporal_store(xn0, out + OUT_ZF  + (size_t)gb * Z_ + 0);
      __builtin_nontemporal_store(xn1, out + OUT_ZF  + (size_t)gb * Z_ + 1);
      __builtin_nontemporal_store(c0[(size_t)gb * Z_ + 0], out + OUT_CZF + (size_t)gb * Z_ + 0);
      __builtin_nontemporal_store(c0[(size_t)gb * Z_ + 1], out + OUT_CZF + (size_t)gb * Z_ + 1);
    }
  }
}

extern "C" void kernel_launch(void* const* d_in, const int* in_sizes, int n_in,
                              void* d_out, int out_size, void* d_ws, size_t ws_size,
                              hipStream_t stream) {
  const float* rnn  = (const float*)d_in[0];
  const float* tauP = (const float*)d_in[1];
  const float* z0   = (const float*)d_in[2];
  const float* c0   = (const float*)d_in[3];
  const float* wuw  = (const float*)d_in[4];
  const float* wub  = (const float*)d_in[5];
  const float* awp  = (const float*)d_in[6];
  const float* abp  = (const float*)d_in[7];
  const float* whw  = (const float*)d_in[8];
  const float* whb  = (const float*)d_in[9];
  const float* Amat = (const float*)d_in[10];
  const float* Bmat = (const float*)d_in[11];
  float* out = (float*)d_out;
  unsigned* flags = (unsigned*)d_ws;
  char* img = (char*)d_ws + FLAGS_BYTES;   // needs ws_size >= 1.06 MB

  // reset flags every call (determinism across graph replays)
  hipMemsetAsync(d_ws, 0, FLAGS_BYTES, stream);
  (void)in_sizes; (void)n_in; (void)out_size; (void)ws_size;

  hipLaunchKernelGGL(lstm_persist, dim3(256), dim3(512), 0, stream,
                     rnn, tauP, z0, c0, wuw, wub, awp, abp, whw, whb, Amat, Bmat,
                     out, flags, img);
}

// Round 4
// 1914.323 us; speedup vs baseline: 4.7617x; 1.2718x over previous
//
#include <hip/hip_runtime.h>
#include <cmath>

// ---------------- problem constants ----------------
#define S_   512
#define Z_   514            // SD + H
#define WUC  516            // WU_w cols: [x(2) | u(2) | h(512)]

// output float offsets
#define OUT_ZF   67371008   // B*S*Z
#define OUT_CZF  67502592   // + B*Z
#define OUT_COEF 67634176   // + B*Z

// ---------------- workspace layout ----------------
// [0, 32KB)          flags: 256 blocks x 128B (one u32 per 128B line)
// [36KB, 36KB+512KB) h images: [parity(2)][bg(8)] x 32KB, f16 [32 rows][512 units]
#define IMG_BASE  36864
#define IMG_BYTES 32768

typedef __attribute__((ext_vector_type(4))) float f32x4;
typedef __attribute__((ext_vector_type(4))) unsigned u32x4;
typedef __attribute__((ext_vector_type(8))) _Float16 f16x8;

__device__ __forceinline__ f32x4 MF16(f16x8 a, f16x8 b, f32x4 c) {
  return __builtin_amdgcn_mfma_f32_16x16x32_f16(a, b, c, 0, 0, 0);
}
// system-scope (sc0 sc1) coherent ops — round-2-proven encoding
__device__ __forceinline__ u32x4 ld16c(const void* p) {
  u32x4 r;
  asm volatile("global_load_dwordx4 %0, %1, off sc0 sc1" : "=v"(r) : "v"(p));
  return r;
}
__device__ __forceinline__ void st16c(void* p, u32x4 v) {
  asm volatile("global_store_dwordx4 %0, %1, off sc0 sc1" :: "v"(p), "v"(v) : "memory");
}
__device__ __forceinline__ void st4c(unsigned* p, unsigned v) {
  asm volatile("global_store_dword %0, %1, off sc0 sc1" :: "v"(p), "v"(v) : "memory");
}
// load + in-asm vmcnt drain (self-contained: result valid on return)
__device__ __forceinline__ unsigned ld4w(const unsigned* p) {
  unsigned r;
  asm volatile("global_load_dword %0, %1, off sc0 sc1\n\ts_waitcnt vmcnt(0)"
               : "=v"(r) : "v"(p) : "memory");
  return r;
}
__device__ __forceinline__ float sigm(float x) { return 1.f / (1.f + expf(-x)); }

// grid: 256 blocks = bg(8) x gg(32); block: 512 threads = 8 waves
__global__ __launch_bounds__(512, 2) void lstm_persist(
    const float* __restrict__ rnn, const float* __restrict__ tau,
    const float* __restrict__ z0,  const float* __restrict__ c0,
    const float* __restrict__ wuw, const float* __restrict__ wub,
    const float* __restrict__ awp, const float* __restrict__ abp,
    const float* __restrict__ whw, const float* __restrict__ whb,
    const float* __restrict__ Amat, const float* __restrict__ Bmat,
    float* __restrict__ out, unsigned* __restrict__ flags, char* __restrict__ img)
{
  __shared__ float cscr[8 * 16 * 84];            // 43 KB gate partials + dot cols
  __shared__ unsigned short hpack[2][32][16];    // parity-buffered h pack (f16 bits)
  __shared__ float gwL[4][16][4];                // per-unit x/u weights
  __shared__ float gbL[4][16];                   // per-unit bias

  const int tid = threadIdx.x;
  const int blk = blockIdx.x;
  const int bg  = blk & 7;         // batch group -> rows [bg*32, bg*32+32)
  const int gg  = blk >> 3;        // gate group  -> units [gg*16, gg*16+16)
  const int rb0 = bg * 32;
  const int j0  = gg * 16;
  const int lane = tid & 63;
  const int wv   = tid >> 6;       // wave 0..7
  const int m    = wv & 1;         // M tile (16 rows)
  const int kq   = wv >> 1;        // K quarter (128)
  const int bb   = tid >> 4;       // 0..31 local batch row (pointwise mapping)
  const int jj   = tid & 15;       // unit-in-block
  const int gb   = rb0 + bb;
  const int ln15 = lane & 15;
  const int lq   = lane >> 4;

  // ---------------- prologue: weights -> registers (split f16) ----------------
  f16x8 bHf[4][5], bLf[4][5];
#pragma unroll
  for (int s = 0; s < 4; ++s) {
    const int kbase = kq * 128 + s * 32 + lq * 8;
#pragma unroll
    for (int n = 0; n < 4; ++n) {
      const float* wp = wuw + (size_t)(n * 512 + j0 + ln15) * WUC + 4 + kbase;
      f16x8 vh, vl;
#pragma unroll
      for (int e = 0; e < 8; ++e) {
        float w = wp[e];
        _Float16 hi = (_Float16)w;
        vh[e] = hi;
        vl[e] = (_Float16)(w - (float)hi);
      }
      bHf[s][n] = vh; bLf[s][n] = vl;
    }
    {
      f16x8 vh, vl;
#pragma unroll
      for (int e = 0; e < 8; ++e) {   // n=4: [alpha_w ; Wh_w ; zeros] tile
        int k = kbase + e;
        float w = 0.f;
        if (ln15 < 2)      w = awp[ln15 * 512 + k];
        else if (ln15 < 4) w = whw[(ln15 - 2) * 512 + k];
        _Float16 hi = (_Float16)w;
        vh[e] = hi;
        vl[e] = (_Float16)(w - (float)hi);
      }
      bHf[s][4] = vh; bLf[s][4] = vl;
    }
  }
  // small params
  const float pA00 = Amat[0], pA01 = Amat[1], pA10 = Amat[2], pA11 = Amat[3];
  const float pB0 = Bmat[0], pB1 = Bmat[1];
  const float pab0 = abp[0], pab1 = abp[1], pwb0 = whb[0], pwb1 = whb[1];
  if (tid < 64) {
    const int n = tid >> 4, j = tid & 15;
    const int r = n * 512 + j0 + j;
    gbL[n][j] = wub[r];
    const float* wr = wuw + (size_t)r * WUC;
    gwL[n][j][0] = wr[0]; gwL[n][j][1] = wr[1];
    gwL[n][j][2] = wr[2]; gwL[n][j][3] = wr[3];
  }
  // states (x replicated across the 16 threads of each bb-group)
  float px0 = z0[(size_t)gb * Z_ + 0], px1 = z0[(size_t)gb * Z_ + 1];
  float c_state = c0[(size_t)gb * Z_ + 2 + j0 + jj];
  float u0_prev = 0.f, tau_prev = 0.f, hval = 0.f;
  float alc0 = 0.f, alc1 = 0.f;

  // publish z0 h-slice into parity-1 image
  {
    float hv = z0[(size_t)gb * Z_ + 2 + j0 + jj];
    unsigned hz = (unsigned)__builtin_bit_cast(unsigned short, (_Float16)hv);
    char* p = img + (size_t)(8 + bg) * IMG_BYTES + bb * 1024 + (j0 + jj) * 2;
    asm volatile("global_store_short %0, %1, off sc0 sc1" :: "v"(p), "v"(hz) : "memory");
  }
  asm volatile("s_waitcnt vmcnt(0)" ::: "memory");
  __syncthreads();
  if (tid == 0) st4c(flags + blk * 32, 1u);

  const int fragbase = (m * 16 + ln15) * 1024 + kq * 256 + lq * 16;
  const int mm = bb >> 4, rr = bb & 15;

  // ---------------- main loop ----------------
  for (int t = 0; t < S_; ++t) {
    const float u0v = rnn[((size_t)gb * S_ + t) * 2 + 0];
    const float u1v = rnn[((size_t)gb * S_ + t) * 2 + 1];
    const float tv  = tau[(size_t)gb * S_ + t];

    // deferred harness stores — issued pre-poll so acks land in the poll shadow
    if (t >= 1)
      __builtin_nontemporal_store(hval, out + ((size_t)gb * S_ + (t - 1)) * Z_ + 2 + j0 + jj);
    if (t >= 2 && gg == 0 && jj == 0) {
      const size_t ob = ((size_t)gb * S_ + (t - 2)) * Z_;
      __builtin_nontemporal_store(px0, out + ob + 0);
      __builtin_nontemporal_store(px1, out + ob + 1);
      const size_t cb = OUT_COEF + ((size_t)gb * S_ + (t - 2)) * 2;
      __builtin_nontemporal_store(alc0, out + cb + 0);
      __builtin_nontemporal_store(alc1, out + cb + 1);
    }

    // wave 7 polls the 32 group flags (one 128B line per lane); B3 releases all
    if (wv == 7) {
      const unsigned tgt = (unsigned)(t + 1);
      const unsigned* fp = flags + ((size_t)(lane & 31) * 8 + bg) * 32;
      for (;;) {
        unsigned v = ld4w(fp);
        if (__all((int)(v >= tgt))) break;
        __builtin_amdgcn_s_sleep(1);
      }
    }
    __syncthreads();   // B3

    // A-fragments of h(t-1) straight from the group image
    const char* baseR = img + (size_t)((((t & 1) ^ 1)) * 8 + bg) * IMG_BYTES + fragbase;
    u32x4 AH[4];
#pragma unroll
    for (int s = 0; s < 4; ++s) AH[s] = ld16c(baseR + s * 64);
    asm volatile("s_waitcnt vmcnt(0)" ::: "memory");
    __builtin_amdgcn_sched_barrier(0);

    f32x4 a0 = {0,0,0,0}, a1 = {0,0,0,0}, a2 = {0,0,0,0}, a3 = {0,0,0,0}, a4 = {0,0,0,0};
#pragma unroll
    for (int s = 0; s < 4; ++s) {
      f16x8 ah = __builtin_bit_cast(f16x8, AH[s]);
      a0 = MF16(ah, bHf[s][0], a0); a0 = MF16(ah, bLf[s][0], a0);
      a1 = MF16(ah, bHf[s][1], a1); a1 = MF16(ah, bLf[s][1], a1);
      a2 = MF16(ah, bHf[s][2], a2); a2 = MF16(ah, bLf[s][2], a2);
      a3 = MF16(ah, bHf[s][3], a3); a3 = MF16(ah, bLf[s][3], a3);
      a4 = MF16(ah, bHf[s][4], a4); a4 = MF16(ah, bLf[s][4], a4);
    }
    {
      const int Rb = (kq * 2 + m) * 16 + lq * 4;
#pragma unroll
      for (int r = 0; r < 4; ++r) {
        float* cp = cscr + (size_t)(Rb + r) * 84;
        cp[0 * 16 + ln15] = a0[r];
        cp[1 * 16 + ln15] = a1[r];
        cp[2 * 16 + ln15] = a2[r];
        cp[3 * 16 + ln15] = a3[r];
        cp[4 * 16 + ln15] = a4[r];
      }
    }
    __syncthreads();   // B1

    // gate sums + alpha/Wh dots
    float g0 = 0, g1 = 0, g2 = 0, g3 = 0, d0 = 0, d1 = 0, d2 = 0, d3 = 0;
#pragma unroll
    for (int q = 0; q < 4; ++q) {
      const float* cp = cscr + (size_t)((q * 2 + mm) * 16 + rr) * 84;
      g0 += cp[0 * 16 + jj]; g1 += cp[1 * 16 + jj];
      g2 += cp[2 * 16 + jj]; g3 += cp[3 * 16 + jj];
      d0 += cp[64]; d1 += cp[65]; d2 += cp[66]; d3 += cp[67];
    }
    // finalize x(t-1) (replicated per-thread, uniform within each bb-group)
    if (t > 0) {
      const float al0 = sigm(d0 + pab0), al1 = sigm(d1 + pab1);
      const float wh0 = d2 + pwb0, wh1 = d3 + pwb1;
      const float xm0 = px0 + tau_prev * (pA00 * px0 + pA01 * px1 + pB0 * u0_prev);
      const float xm1 = px1 + tau_prev * (pA10 * px0 + pA11 * px1 + pB1 * u0_prev);
      px0 = al0 * xm0 + (1.f - al0) * wh0;
      px1 = al1 * xm1 + (1.f - al1) * wh1;
      alc0 = al0; alc1 = al1;
    }
    // pointwise LSTM
    g0 += gbL[0][jj] + px0 * gwL[0][jj][0] + px1 * gwL[0][jj][1] + u0v * gwL[0][jj][2] + u1v * gwL[0][jj][3];
    g1 += gbL[1][jj] + px0 * gwL[1][jj][0] + px1 * gwL[1][jj][1] + u0v * gwL[1][jj][2] + u1v * gwL[1][jj][3];
    g2 += gbL[2][jj] + px0 * gwL[2][jj][0] + px1 * gwL[2][jj][1] + u0v * gwL[2][jj][2] + u1v * gwL[2][jj][3];
    g3 += gbL[3][jj] + px0 * gwL[3][jj][0] + px1 * gwL[3][jj][1] + u0v * gwL[3][jj][2] + u1v * gwL[3][jj][3];
    const float ci = sigm(g0), cf = sigm(g1), co = sigm(g3);
    c_state = cf * c_state + ci * tanhf(g2);
    hval = co * tanhf(c_state);
    u0_prev = u0v; tau_prev = tv;

    // pack h(t) into LDS (parity-buffered)
    hpack[t & 1][bb][jj] = __builtin_bit_cast(unsigned short, (_Float16)hval);
    __syncthreads();   // B2

    // wave 0 publishes the block's 1KB slice + flag; other waves run ahead
    if (wv == 0) {
      const int row = lane >> 1, half = lane & 1;
      u32x4 d = *(const u32x4*)&hpack[t & 1][row][half * 8];
      char* wp = img + (size_t)((t & 1) * 8 + bg) * IMG_BYTES + row * 1024 + (j0 + half * 8) * 2;
      st16c(wp, d);
      asm volatile("s_waitcnt vmcnt(0)" ::: "memory");
      if (lane == 0) st4c(flags + blk * 32, (unsigned)(t + 2));
    }
  }

  // ---------------- tail: pending stores + alpha/x for t = 511 ----------------
  __builtin_nontemporal_store(hval, out + ((size_t)gb * S_ + 511) * Z_ + 2 + j0 + jj);
  __builtin_nontemporal_store(hval,    out + OUT_ZF  + (size_t)gb * Z_ + 2 + j0 + jj);
  __builtin_nontemporal_store(c_state, out + OUT_CZF + (size_t)gb * Z_ + 2 + j0 + jj);
  if (gg == 0 && jj == 0) {
    const size_t ob = ((size_t)gb * S_ + 510) * Z_;
    __builtin_nontemporal_store(px0, out + ob + 0);
    __builtin_nontemporal_store(px1, out + ob + 1);
    const size_t cb = OUT_COEF + ((size_t)gb * S_ + 510) * 2;
    __builtin_nontemporal_store(alc0, out + cb + 0);
    __builtin_nontemporal_store(alc1, out + cb + 1);
  }

  // wait for h(511) from all group blocks
  if (wv == 7) {
    const unsigned* fp = flags + ((size_t)(lane & 31) * 8 + bg) * 32;
    for (;;) {
      unsigned v = ld4w(fp);
      if (__all((int)(v >= (unsigned)(S_ + 1)))) break;
      __builtin_amdgcn_s_sleep(1);
    }
  }
  __syncthreads();
  {
    const char* baseR = img + (size_t)(8 + bg) * IMG_BYTES + fragbase;  // parity 1 = h(511)
    f32x4 a4 = {0,0,0,0};
#pragma unroll
    for (int s = 0; s < 4; ++s) {
      u32x4 AHs = ld16c(baseR + s * 64);
      asm volatile("s_waitcnt vmcnt(0)" ::: "memory");
      __builtin_amdgcn_sched_barrier(0);
      f16x8 ah = __builtin_bit_cast(f16x8, AHs);
      a4 = MF16(ah, bHf[s][4], a4); a4 = MF16(ah, bLf[s][4], a4);
    }
    const int Rb = (kq * 2 + m) * 16 + lq * 4;
#pragma unroll
    for (int r = 0; r < 4; ++r)
      cscr[(size_t)(Rb + r) * 84 + 64 + ln15] = a4[r];
  }
  __syncthreads();
  {
    float d0 = 0, d1 = 0, d2 = 0, d3 = 0;
#pragma unroll
    for (int q = 0; q < 4; ++q) {
      const float* cp = cscr + (size_t)((q * 2 + mm) * 16 + rr) * 84;
      d0 += cp[64]; d1 += cp[65]; d2 += cp[66]; d3 += cp[67];
    }
    const float al0 = sigm(d0 + pab0), al1 = sigm(d1 + pab1);
    const float wh0 = d2 + pwb0, wh1 = d3 + pwb1;
    const float xm0 = px0 + tau_prev * (pA00 * px0 + pA01 * px1 + pB0 * u0_prev);
    const float xm1 = px1 + tau_prev * (pA10 * px0 + pA11 * px1 + pB1 * u0_prev);
    const float xn0 = al0 * xm0 + (1.f - al0) * wh0;
    const float xn1 = al1 * xm1 + (1.f - al1) * wh1;
    if (gg == 0 && jj == 0) {
      const size_t ob = ((size_t)gb * S_ + 511) * Z_;
      __builtin_nontemporal_store(xn0, out + ob + 0);
      __builtin_nontemporal_store(xn1, out + ob + 1);
      const size_t cb = OUT_COEF + ((size_t)gb * S_ + 511) * 2;
      __builtin_nontemporal_store(al0, out + cb + 0);
      __builtin_nontemporal_store(al1, out + cb + 1);
      __builtin_nontemporal_store(xn0, out + OUT_ZF  + (size_t)gb * Z_ + 0);
      __builtin_nontemporal_store(xn1, out + OUT_ZF  + (size_t)gb * Z_ + 1);
      __builtin_nontemporal_store(c0[(size_t)gb * Z_ + 0], out + OUT_CZF + (size_t)gb * Z_ + 0);
      __builtin_nontemporal_store(c0[(size_t)gb * Z_ + 1], out + OUT_CZF + (size_t)gb * Z_ + 1);
    }
  }
}

extern "C" void kernel_launch(void* const* d_in, const int* in_sizes, int n_in,
                              void* d_out, int out_size, void* d_ws, size_t ws_size,
                              hipStream_t stream) {
  const float* rnn  = (const float*)d_in[0];
  const float* tauP = (const float*)d_in[1];
  const float* z0   = (const float*)d_in[2];
  const float* c0   = (const float*)d_in[3];
  const float* wuw  = (const float*)d_in[4];
  const float* wub  = (const float*)d_in[5];
  const float* awp  = (const float*)d_in[6];
  const float* abp  = (const float*)d_in[7];
  const float* whw  = (const float*)d_in[8];
  const float* whb  = (const float*)d_in[9];
  const float* Amat = (const float*)d_in[10];
  const float* Bmat = (const float*)d_in[11];
  float* out = (float*)d_out;
  unsigned* flags = (unsigned*)d_ws;
  char* img = (char*)d_ws + IMG_BASE;   // uses ws up to 36,864 + 512KB

  // reset flags every call (determinism across graph replays)
  hipMemsetAsync(d_ws, 0, IMG_BASE, stream);
  (void)in_sizes; (void)n_in; (void)out_size; (void)ws_size;

  hipLaunchKernelGGL(lstm_persist, dim3(256), dim3(512), 0, stream,
                     rnn, tauP, z0, c0, wuw, wub, awp, abp, whw, whb, Amat, Bmat,
                     out, flags, img);
}

// Round 6
// 1456.757 us; speedup vs baseline: 6.2574x; 1.3141x over previous
//
#include <hip/hip_runtime.h>
#include <cmath>

// ---------------- problem constants ----------------
#define S_   512
#define Z_   514            // SD + H
#define WUC  516            // WU_w cols: [x(2) | u(2) | h(512)]

// output float offsets
#define OUT_ZF   67371008   // B*S*Z
#define OUT_CZF  67502592   // + B*Z
#define OUT_COEF 67634176   // + B*Z

// ---------------- workspace layout ----------------
// img: [slot(4)][bg(8)] x 32KB f16 image [32 rows][512 units]; 1MB total.
// Launch-time memset 0xFF poisons everything (0xFFFF = f16 NaN sentinel;
// real h / z0-h are always finite, so sentinel is unambiguous).
#define IMG_BYTES 32768

typedef __attribute__((ext_vector_type(4))) float f32x4;
typedef __attribute__((ext_vector_type(4))) unsigned u32x4;
typedef __attribute__((ext_vector_type(8))) _Float16 f16x8;

__device__ __forceinline__ f32x4 MF16(f16x8 a, f16x8 b, f32x4 c) {
  return __builtin_amdgcn_mfma_f32_16x16x32_f16(a, b, c, 0, 0, 0);
}
// system-scope (sc0 sc1) coherent ops — round-2/4-proven encoding
__device__ __forceinline__ u32x4 ld16c(const void* p) {
  u32x4 r;
  asm volatile("global_load_dwordx4 %0, %1, off sc0 sc1" : "=v"(r) : "v"(p));
  return r;
}
__device__ __forceinline__ void st16c(void* p, u32x4 v) {
  asm volatile("global_store_dwordx4 %0, %1, off sc0 sc1" :: "v"(p), "v"(v) : "memory");
}
__device__ __forceinline__ void st4c(void* p, unsigned v) {
  asm volatile("global_store_dword %0, %1, off sc0 sc1" :: "v"(p), "v"(v) : "memory");
}
// chunk ready: no dword still holds the poison pattern in its low half
// (producer 4B stores are dword-atomic: each dword is all-poison or all-data)
__device__ __forceinline__ bool rdy(u32x4 v) {
  unsigned b = (unsigned)((v[0] & 0xFFFFu) == 0xFFFFu) |
               (unsigned)((v[1] & 0xFFFFu) == 0xFFFFu) |
               (unsigned)((v[2] & 0xFFFFu) == 0xFFFFu) |
               (unsigned)((v[3] & 0xFFFFu) == 0xFFFFu);
  return b == 0u;
}
// overflow-safe fast transcendentals (inf-graceful, no NaN paths)
__device__ __forceinline__ float sigm(float x)  { return 1.f / (1.f + __expf(-x)); }
__device__ __forceinline__ float ftanh(float x) { return 2.f / (1.f + __expf(-2.f * x)) - 1.f; }

// cscr swizzled index: stride 112 floats, XOR bit4 of col with (row>>2)&1.
// Writes (rows 4 apart) and reads (rows 1 apart) both land 2-way = free.
__device__ __forceinline__ int crow(int row) { return row * 112; }
__device__ __forceinline__ int cxor(int row) { return ((row >> 2) & 1) << 4; }

// grid: 256 blocks = bg(8) x gg(32); block: 512 threads = 8 waves
__global__ __launch_bounds__(512, 2) void lstm_persist(
    const float* __restrict__ rnn, const float* __restrict__ tau,
    const float* __restrict__ z0,  const float* __restrict__ c0,
    const float* __restrict__ wuw, const float* __restrict__ wub,
    const float* __restrict__ awp, const float* __restrict__ abp,
    const float* __restrict__ whw, const float* __restrict__ whb,
    const float* __restrict__ Amat, const float* __restrict__ Bmat,
    float* __restrict__ out, char* __restrict__ img)
{
  __shared__ float cscr[8 * 16 * 112];   // 56 KB, swizzled (gates 0..63, dots 64..67)
  __shared__ float gwL[4][16][4];        // per-unit x/u weights
  __shared__ float gbL[4][16];           // per-unit bias

  const int tid = threadIdx.x;
  const int blk = blockIdx.x;
  const int bg  = blk & 7;         // batch group -> rows [bg*32, bg*32+32)
  const int gg  = blk >> 3;        // gate group  -> units [gg*16, gg*16+16)
  const int rb0 = bg * 32;
  const int j0  = gg * 16;
  const int lane = tid & 63;
  const int wv   = tid >> 6;       // wave 0..7
  const int m    = wv & 1;         // M tile (16 rows)
  const int kq   = wv >> 1;        // K quarter (128)
  const int bb   = tid >> 4;       // 0..31 local batch row (pointwise mapping)
  const int jj   = tid & 15;       // unit-in-block
  const int gb   = rb0 + bb;
  const int ln15 = lane & 15;
  const int lq   = lane >> 4;

  // ---------------- prologue: weights -> registers (split f16) ----------------
  f16x8 bHf[4][5], bLf[4][5];
#pragma unroll
  for (int s = 0; s < 4; ++s) {
    const int kbase = kq * 128 + s * 32 + lq * 8;
#pragma unroll
    for (int n = 0; n < 4; ++n) {
      const float* wp = wuw + (size_t)(n * 512 + j0 + ln15) * WUC + 4 + kbase;
      f16x8 vh, vl;
#pragma unroll
      for (int e = 0; e < 8; ++e) {
        float w = wp[e];
        _Float16 hi = (_Float16)w;
        vh[e] = hi;
        vl[e] = (_Float16)(w - (float)hi);
      }
      bHf[s][n] = vh; bLf[s][n] = vl;
    }
    {
      f16x8 vh, vl;
#pragma unroll
      for (int e = 0; e < 8; ++e) {   // n=4: [alpha_w ; Wh_w ; zeros] tile
        int k = kbase + e;
        float w = 0.f;
        if (ln15 < 2)      w = awp[ln15 * 512 + k];
        else if (ln15 < 4) w = whw[(ln15 - 2) * 512 + k];
        _Float16 hi = (_Float16)w;
        vh[e] = hi;
        vl[e] = (_Float16)(w - (float)hi);
      }
      bHf[s][4] = vh; bLf[s][4] = vl;
    }
  }
  // small params
  const float pA00 = Amat[0], pA01 = Amat[1], pA10 = Amat[2], pA11 = Amat[3];
  const float pB0 = Bmat[0], pB1 = Bmat[1];
  const float pab0 = abp[0], pab1 = abp[1], pwb0 = whb[0], pwb1 = whb[1];
  if (tid < 64) {
    const int n = tid >> 4, j = tid & 15;
    const int r = n * 512 + j0 + j;
    gbL[n][j] = wub[r];
    const float* wr = wuw + (size_t)r * WUC;
    gwL[n][j][0] = wr[0]; gwL[n][j][1] = wr[1];
    gwL[n][j][2] = wr[2]; gwL[n][j][3] = wr[3];
  }
  // states (x replicated across the 16 threads of each bb-group)
  float px0 = z0[(size_t)gb * Z_ + 0], px1 = z0[(size_t)gb * Z_ + 1];
  float c_state = c0[(size_t)gb * Z_ + 2 + j0 + jj];
  float u0_prev = 0.f, tau_prev = 0.f, hval = 0.f;
  float alc0 = 0.f, alc1 = 0.f;

  // publish z0 h-slice into slot 3 ("h(-1)"), pair-packed fire-and-forget
  {
    float hv = z0[(size_t)gb * Z_ + 2 + j0 + jj];
    unsigned hz = (unsigned)__builtin_bit_cast(unsigned short, (_Float16)hv);
    unsigned ph = (unsigned)__shfl_xor((int)hz, 1);
    if ((jj & 1) == 0)
      st4c(img + (size_t)(3 * 8 + bg) * IMG_BYTES + bb * 1024 + (j0 + jj) * 2,
           hz | (ph << 16));
  }
  __syncthreads();

  const int fragbase = (m * 16 + ln15) * 1024 + kq * 256 + lq * 16;
  const int mm = bb >> 4, rr = bb & 15;

  // ---------------- main loop ----------------
  for (int t = 0; t < S_; ++t) {
    const float u0v = rnn[((size_t)gb * S_ + t) * 2 + 0];
    const float u1v = rnn[((size_t)gb * S_ + t) * 2 + 1];
    const float tv  = tau[(size_t)gb * S_ + t];

    // deferred harness stores — acks complete in the spin shadow
    if (t >= 1)
      __builtin_nontemporal_store(hval, out + ((size_t)gb * S_ + (t - 1)) * Z_ + 2 + j0 + jj);
    if (t >= 2 && gg == 0 && jj == 0) {
      const size_t ob = ((size_t)gb * S_ + (t - 2)) * Z_;
      __builtin_nontemporal_store(px0, out + ob + 0);
      __builtin_nontemporal_store(px1, out + ob + 1);
      const size_t cb = OUT_COEF + ((size_t)gb * S_ + (t - 2)) * 2;
      __builtin_nontemporal_store(alc0, out + cb + 0);
      __builtin_nontemporal_store(alc1, out + cb + 1);
    }

    // self-validating spin: the poll IS the fragment load (slot (t-1)&3).
    // RULE #18 FENCE: sched_barrier(0) after the vmcnt drain, else the compiler
    // schedules the register-only rdy() checks BEFORE the waitcnt (reading the
    // load destination regs before the load completes) -> garbage passes -> NaN.
    const char* baseR = img + (size_t)(((t + 3) & 3) * 8 + bg) * IMG_BYTES + fragbase;
    u32x4 A0, A1, A2, A3;
    {
      bool ok0 = false, ok1 = false, ok2 = false, ok3 = false;
      for (;;) {
        if (!ok0) A0 = ld16c(baseR + 0);
        if (!ok1) A1 = ld16c(baseR + 64);
        if (!ok2) A2 = ld16c(baseR + 128);
        if (!ok3) A3 = ld16c(baseR + 192);
        asm volatile("s_waitcnt vmcnt(0)" ::: "memory");
        __builtin_amdgcn_sched_barrier(0);
        ok0 = rdy(A0); ok1 = rdy(A1); ok2 = rdy(A2); ok3 = rdy(A3);
        if (ok0 && ok1 && ok2 && ok3) break;
        __builtin_amdgcn_s_sleep(1);
      }
    }
    __builtin_amdgcn_sched_barrier(0);

    f32x4 a0 = {0,0,0,0}, a1 = {0,0,0,0}, a2 = {0,0,0,0}, a3 = {0,0,0,0}, a4 = {0,0,0,0};
#pragma unroll
    for (int s = 0; s < 4; ++s) {
      u32x4 As = (s == 0) ? A0 : (s == 1) ? A1 : (s == 2) ? A2 : A3;
      f16x8 ah = __builtin_bit_cast(f16x8, As);
      a0 = MF16(ah, bHf[s][0], a0); a0 = MF16(ah, bLf[s][0], a0);
      a1 = MF16(ah, bHf[s][1], a1); a1 = MF16(ah, bLf[s][1], a1);
      a2 = MF16(ah, bHf[s][2], a2); a2 = MF16(ah, bLf[s][2], a2);
      a3 = MF16(ah, bHf[s][3], a3); a3 = MF16(ah, bLf[s][3], a3);
      a4 = MF16(ah, bHf[s][4], a4); a4 = MF16(ah, bLf[s][4], a4);
    }
    {
      const int Rb = (kq * 2 + m) * 16 + lq * 4;
#pragma unroll
      for (int r = 0; r < 4; ++r) {
        const int row = Rb + r;
        float* cp = cscr + crow(row);
        const int xb = cxor(row);
        cp[(0 * 16 ^ xb) + ln15] = a0[r];
        cp[(1 * 16 ^ xb) + ln15] = a1[r];
        cp[(2 * 16 ^ xb) + ln15] = a2[r];
        cp[(3 * 16 ^ xb) + ln15] = a3[r];
        cp[(4 * 16 ^ xb) + ln15] = a4[r];
      }
    }
    __syncthreads();   // B1

    // gate sums + alpha/Wh dots (dot quad is one aligned float4)
    float g0 = 0, g1 = 0, g2 = 0, g3 = 0, d0 = 0, d1 = 0, d2 = 0, d3 = 0;
#pragma unroll
    for (int q = 0; q < 4; ++q) {
      const int row = (q * 2 + mm) * 16 + rr;
      const float* cp = cscr + crow(row);
      const int xb = cxor(row);
      g0 += cp[(0 * 16 ^ xb) + jj]; g1 += cp[(1 * 16 ^ xb) + jj];
      g2 += cp[(2 * 16 ^ xb) + jj]; g3 += cp[(3 * 16 ^ xb) + jj];
      const f32x4 dv = *(const f32x4*)(cp + (64 ^ xb));
      d0 += dv[0]; d1 += dv[1]; d2 += dv[2]; d3 += dv[3];
    }
    // finalize x(t-1) (replicated per-thread, uniform within each bb-group)
    if (t > 0) {
      const float al0 = sigm(d0 + pab0), al1 = sigm(d1 + pab1);
      const float wh0 = d2 + pwb0, wh1 = d3 + pwb1;
      const float xm0 = px0 + tau_prev * (pA00 * px0 + pA01 * px1 + pB0 * u0_prev);
      const float xm1 = px1 + tau_prev * (pA10 * px0 + pA11 * px1 + pB1 * u0_prev);
      px0 = al0 * xm0 + (1.f - al0) * wh0;
      px1 = al1 * xm1 + (1.f - al1) * wh1;
      alc0 = al0; alc1 = al1;
    }
    // pointwise LSTM
    g0 += gbL[0][jj] + px0 * gwL[0][jj][0] + px1 * gwL[0][jj][1] + u0v * gwL[0][jj][2] + u1v * gwL[0][jj][3];
    g1 += gbL[1][jj] + px0 * gwL[1][jj][0] + px1 * gwL[1][jj][1] + u0v * gwL[1][jj][2] + u1v * gwL[1][jj][3];
    g2 += gbL[2][jj] + px0 * gwL[2][jj][0] + px1 * gwL[2][jj][1] + u0v * gwL[2][jj][2] + u1v * gwL[2][jj][3];
    g3 += gbL[3][jj] + px0 * gwL[3][jj][0] + px1 * gwL[3][jj][1] + u0v * gwL[3][jj][2] + u1v * gwL[3][jj][3];
    const float ci = sigm(g0), cf = sigm(g1), co = sigm(g3);
    c_state = cf * c_state + ci * ftanh(g2);
    hval = co * ftanh(c_state);
    u0_prev = u0v; tau_prev = tv;

    // publish h(t) -> slot t&3: pair-packed 4B stores, fire-and-forget
    {
      unsigned hz = (unsigned)__builtin_bit_cast(unsigned short, (_Float16)hval);
      unsigned ph = (unsigned)__shfl_xor((int)hz, 1);
      if ((jj & 1) == 0)
        st4c(img + (size_t)((t & 3) * 8 + bg) * IMG_BYTES + bb * 1024 + (j0 + jj) * 2,
             hz | (ph << 16));
    }
    // wave 0 re-poisons this block's slice of slot (t+2)&3 (holds dead h(t-2);
    // drained by wave 0's next spin vmcnt(0), ordered before t+2's publish by B1)
    if (wv == 0) {
      const int row = lane >> 1, half = lane & 1;
      u32x4 poison = {~0u, ~0u, ~0u, ~0u};
      st16c(img + (size_t)(((t + 2) & 3) * 8 + bg) * IMG_BYTES + row * 1024 + (j0 + half * 8) * 2,
            poison);
    }
    __syncthreads();   // B2 (also orders cscr reads of t vs writes of t+1)
  }

  // ---------------- tail: pending stores + alpha/x for t = 511 ----------------
  __builtin_nontemporal_store(hval, out + ((size_t)gb * S_ + 511) * Z_ + 2 + j0 + jj);
  __builtin_nontemporal_store(hval,    out + OUT_ZF  + (size_t)gb * Z_ + 2 + j0 + jj);
  __builtin_nontemporal_store(c_state, out + OUT_CZF + (size_t)gb * Z_ + 2 + j0 + jj);
  if (gg == 0 && jj == 0) {
    const size_t ob = ((size_t)gb * S_ + 510) * Z_;
    __builtin_nontemporal_store(px0, out + ob + 0);
    __builtin_nontemporal_store(px1, out + ob + 1);
    const size_t cb = OUT_COEF + ((size_t)gb * S_ + 510) * 2;
    __builtin_nontemporal_store(alc0, out + cb + 0);
    __builtin_nontemporal_store(alc1, out + cb + 1);
  }

  // final alpha/Wh GEMM over h(511) (slot 511&3 = 3), NaN-spin validated
  {
    const char* baseR = img + (size_t)(3 * 8 + bg) * IMG_BYTES + fragbase;
    u32x4 A0, A1, A2, A3;
    {
      bool ok0 = false, ok1 = false, ok2 = false, ok3 = false;
      for (;;) {
        if (!ok0) A0 = ld16c(baseR + 0);
        if (!ok1) A1 = ld16c(baseR + 64);
        if (!ok2) A2 = ld16c(baseR + 128);
        if (!ok3) A3 = ld16c(baseR + 192);
        asm volatile("s_waitcnt vmcnt(0)" ::: "memory");
        __builtin_amdgcn_sched_barrier(0);
        ok0 = rdy(A0); ok1 = rdy(A1); ok2 = rdy(A2); ok3 = rdy(A3);
        if (ok0 && ok1 && ok2 && ok3) break;
        __builtin_amdgcn_s_sleep(1);
      }
    }
    __builtin_amdgcn_sched_barrier(0);
    f32x4 a4 = {0,0,0,0};
#pragma unroll
    for (int s = 0; s < 4; ++s) {
      u32x4 As = (s == 0) ? A0 : (s == 1) ? A1 : (s == 2) ? A2 : A3;
      f16x8 ah = __builtin_bit_cast(f16x8, As);
      a4 = MF16(ah, bHf[s][4], a4); a4 = MF16(ah, bLf[s][4], a4);
    }
    const int Rb = (kq * 2 + m) * 16 + lq * 4;
#pragma unroll
    for (int r = 0; r < 4; ++r) {
      const int row = Rb + r;
      cscr[crow(row) + ((4 * 16) ^ cxor(row)) + ln15] = a4[r];
    }
  }
  __syncthreads();
  {
    float d0 = 0, d1 = 0, d2 = 0, d3 = 0;
#pragma unroll
    for (int q = 0; q < 4; ++q) {
      const int row = (q * 2 + mm) * 16 + rr;
      const f32x4 dv = *(const f32x4*)(cscr + crow(row) + (64 ^ cxor(row)));
      d0 += dv[0]; d1 += dv[1]; d2 += dv[2]; d3 += dv[3];
    }
    const float al0 = sigm(d0 + pab0), al1 = sigm(d1 + pab1);
    const float wh0 = d2 + pwb0, wh1 = d3 + pwb1;
    const float xm0 = px0 + tau_prev * (pA00 * px0 + pA01 * px1 + pB0 * u0_prev);
    const float xm1 = px1 + tau_prev * (pA10 * px0 + pA11 * px1 + pB1 * u0_prev);
    const float xn0 = al0 * xm0 + (1.f - al0) * wh0;
    const float xn1 = al1 * xm1 + (1.f - al1) * wh1;
    if (gg == 0 && jj == 0) {
      const size_t ob = ((size_t)gb * S_ + 511) * Z_;
      __builtin_nontemporal_store(xn0, out + ob + 0);
      __builtin_nontemporal_store(xn1, out + ob + 1);
      const size_t cb = OUT_COEF + ((size_t)gb * S_ + 511) * 2;
      __builtin_nontemporal_store(al0, out + cb + 0);
      __builtin_nontemporal_store(al1, out + cb + 1);
      __builtin_nontemporal_store(xn0, out + OUT_ZF  + (size_t)gb * Z_ + 0);
      __builtin_nontemporal_store(xn1, out + OUT_ZF  + (size_t)gb * Z_ + 1);
      __builtin_nontemporal_store(c0[(size_t)gb * Z_ + 0], out + OUT_CZF + (size_t)gb * Z_ + 0);
      __builtin_nontemporal_store(c0[(size_t)gb * Z_ + 1], out + OUT_CZF + (size_t)gb * Z_ + 1);
    }
  }
}

extern "C" void kernel_launch(void* const* d_in, const int* in_sizes, int n_in,
                              void* d_out, int out_size, void* d_ws, size_t ws_size,
                              hipStream_t stream) {
  const float* rnn  = (const float*)d_in[0];
  const float* tauP = (const float*)d_in[1];
  const float* z0   = (const float*)d_in[2];
  const float* c0   = (const float*)d_in[3];
  const float* wuw  = (const float*)d_in[4];
  const float* wub  = (const float*)d_in[5];
  const float* awp  = (const float*)d_in[6];
  const float* abp  = (const float*)d_in[7];
  const float* whw  = (const float*)d_in[8];
  const float* whb  = (const float*)d_in[9];
  const float* Amat = (const float*)d_in[10];
  const float* Bmat = (const float*)d_in[11];
  float* out = (float*)d_out;
  char* img = (char*)d_ws;   // 1 MB: 4 slots x 8 bg x 32KB (ws >= 1.08MB proven round 2)

  // poison all image slots to 0xFFFF (f16 NaN sentinel) every call — part of the
  // captured graph, so every replay starts from the identical poisoned state
  hipMemsetAsync(d_ws, 0xFF, 4 * 8 * IMG_BYTES, stream);
  (void)in_sizes; (void)n_in; (void)out_size; (void)ws_size;

  hipLaunchKernelGGL(lstm_persist, dim3(256), dim3(512), 0, stream,
                     rnn, tauP, z0, c0, wuw, wub, awp, abp, whw, whb, Amat, Bmat,
                     out, img);
}